// Round 1
// baseline (4473.035 us; speedup 1.0000x reference)
//
#include <hip/hip_runtime.h>
#include <hip/hip_bf16.h>
#include <math.h>

// ---------------- problem constants ----------------
#define L_SEQ   4096
#define D_MODEL 2048
#define NQ      16
#define NKV     8
#define HD      128
#define SCALING 0.08838834764831845f   // 128^-0.5
#define K_SEL   1024                   // L * 0.25

// ============================================================
// Kernel 1: C[M][N] = gather(embed_table, ids)[M][2048] @ W[2048][N]
// fp32, 64x64 tile, 256 threads, 4x4 per thread, BK=16
// ============================================================
__global__ __launch_bounds__(256) void gemm_embed(
    const int* __restrict__ ids, const float* __restrict__ table,
    const float* __restrict__ W, float* __restrict__ C, int N) {
  __shared__ float As[16][68];  // [k][m], pad 68 -> 272B rows (16B multiple)
  __shared__ float Bs[16][68];  // [k][n]
  const int tid = threadIdx.x;
  const int tx = tid & 15, ty = tid >> 4;
  const int bm = blockIdx.y * 64, bn = blockIdx.x * 64;

  const int arow = tid >> 2;            // 0..63
  const int acol4 = (tid & 3) * 4;      // 0,4,8,12
  const long arowbase = (long)ids[bm + arow] * D_MODEL;
  const int kr = tid >> 4;              // 0..15
  const int cc = (tid & 15) * 4;        // 0..60

  float acc[4][4] = {};
  for (int k0 = 0; k0 < D_MODEL; k0 += 16) {
    float4 av = *(const float4*)(table + arowbase + k0 + acol4);
    As[acol4 + 0][arow] = av.x; As[acol4 + 1][arow] = av.y;
    As[acol4 + 2][arow] = av.z; As[acol4 + 3][arow] = av.w;
    float4 bv = *(const float4*)(W + (long)(k0 + kr) * N + bn + cc);
    Bs[kr][cc + 0] = bv.x; Bs[kr][cc + 1] = bv.y;
    Bs[kr][cc + 2] = bv.z; Bs[kr][cc + 3] = bv.w;
    __syncthreads();
#pragma unroll
    for (int kk = 0; kk < 16; ++kk) {
      const float4 a = *(const float4*)&As[kk][ty * 4];
      const float4 b = *(const float4*)&Bs[kk][tx * 4];
      const float avv[4] = {a.x, a.y, a.z, a.w};
      const float bvv[4] = {b.x, b.y, b.z, b.w};
#pragma unroll
      for (int e = 0; e < 4; ++e)
#pragma unroll
        for (int f = 0; f < 4; ++f) acc[e][f] += avv[e] * bvv[f];
    }
    __syncthreads();
  }
#pragma unroll
  for (int e = 0; e < 4; ++e) {
    float4 o; o.x = acc[e][0]; o.y = acc[e][1]; o.z = acc[e][2]; o.w = acc[e][3];
    *(float4*)(C + (long)(bm + ty * 4 + e) * N + bn + tx * 4) = o;
  }
}

// ============================================================
// Kernel 2: RoPE in place on X[L][NH*128]; one thread per (i,h,t<64) pair
// ============================================================
__global__ void rope_inplace(float* __restrict__ X, int NH, int lognh) {
  const int g = blockIdx.x * blockDim.x + threadIdx.x;
  const int t = g & 63;
  const int h = (g >> 6) & (NH - 1);
  const int i = g >> (6 + lognh);
  const float e = (float)(2 * t) / 128.0f;
  const float invf = 1.0f / powf(10000.0f, e);
  const float ang = (float)i * invf;
  const float c = cosf(ang), s = sinf(ang);
  const long base = (long)i * (NH * HD) + h * HD + t;
  const float x1 = X[base], x2 = X[base + 64];
  X[base]      = x1 * c - x2 * s;
  X[base + 64] = x2 * c + x1 * s;
}

// ============================================================
// Kernel 3: causal softmax column-sum accumulation.
// Block = (q-tile of 64, head). Pass 1: row denominators Z (no max-sub:
// softcap bounds |s|<=50, actual |s|~2e-3 -> exp safe). Pass 2: re-compute
// scores, accumulate exp(s)/Z into importance via atomics.
// LDS: Qs/Ks stored k-major [128][64] so inner loop reads are ds_read_b128.
// ============================================================
__global__ __launch_bounds__(256) void attn_stats(
    const float* __restrict__ Q,   // [L][NQ*HD]  (roped)
    const float* __restrict__ K,   // [L][NKV*HD] (roped)
    float* __restrict__ imp) {
  __shared__ float Qs[128][64];
  __shared__ float Ks[128][64];
  __shared__ float red[64][17];
  __shared__ float rinv[64];
  const int tid = threadIdx.x;
  const int tx = tid & 15, ty = tid >> 4;
  const int bx = blockIdx.x, h = blockIdx.y;
  const int q0 = bx * 64;
  const int kvh = h >> 1;   // GQA: q head h uses kv head h/2 (jnp.repeat)

  // load Q tile once: Qs[d][r]
#pragma unroll
  for (int it = 0; it < 8; ++it) {
    const int idx = tid + it * 256;     // 2048 float4 slots
    const int r = idx >> 5;
    const int d4 = (idx & 31) * 4;
    float4 v = *(const float4*)(Q + (long)(q0 + r) * (NQ * HD) + h * HD + d4);
    Qs[d4][r] = v.x; Qs[d4 + 1][r] = v.y; Qs[d4 + 2][r] = v.z; Qs[d4 + 3][r] = v.w;
  }
  __syncthreads();

  float rs[4] = {0.f, 0.f, 0.f, 0.f};
  // ---- pass 1: row sums ----
  for (int t = 0; t <= bx; ++t) {
    const int j0 = t * 64;
#pragma unroll
    for (int it = 0; it < 8; ++it) {
      const int idx = tid + it * 256;
      const int r = idx >> 5;
      const int d4 = (idx & 31) * 4;
      float4 v = *(const float4*)(K + (long)(j0 + r) * (NKV * HD) + kvh * HD + d4);
      Ks[d4][r] = v.x; Ks[d4 + 1][r] = v.y; Ks[d4 + 2][r] = v.z; Ks[d4 + 3][r] = v.w;
    }
    __syncthreads();
    float acc[4][4] = {};
#pragma unroll 8
    for (int kk = 0; kk < 128; ++kk) {
      const float4 a = *(const float4*)&Qs[kk][ty * 4];
      const float4 b = *(const float4*)&Ks[kk][tx * 4];
      const float avv[4] = {a.x, a.y, a.z, a.w};
      const float bvv[4] = {b.x, b.y, b.z, b.w};
#pragma unroll
      for (int e = 0; e < 4; ++e)
#pragma unroll
        for (int f = 0; f < 4; ++f) acc[e][f] += avv[e] * bvv[f];
    }
#pragma unroll
    for (int e = 0; e < 4; ++e) {
      const int q = q0 + ty * 4 + e;
#pragma unroll
      for (int f = 0; f < 4; ++f) {
        const int j = j0 + tx * 4 + f;
        if (j <= q) {
          float s = acc[e][f] * SCALING;
          s = 50.0f * tanhf(s * 0.02f);   // softcap
          rs[e] += __expf(s);
        }
      }
    }
    __syncthreads();
  }
  // reduce row sums across tx
#pragma unroll
  for (int e = 0; e < 4; ++e) red[ty * 4 + e][tx] = rs[e];
  __syncthreads();
  if (tid < 64) {
    float z = 0.f;
#pragma unroll
    for (int x = 0; x < 16; ++x) z += red[tid][x];
    rinv[tid] = 1.0f / z;
  }
  __syncthreads();

  // ---- pass 2: column sums ----
  for (int t = 0; t <= bx; ++t) {
    const int j0 = t * 64;
#pragma unroll
    for (int it = 0; it < 8; ++it) {
      const int idx = tid + it * 256;
      const int r = idx >> 5;
      const int d4 = (idx & 31) * 4;
      float4 v = *(const float4*)(K + (long)(j0 + r) * (NKV * HD) + kvh * HD + d4);
      Ks[d4][r] = v.x; Ks[d4 + 1][r] = v.y; Ks[d4 + 2][r] = v.z; Ks[d4 + 3][r] = v.w;
    }
    __syncthreads();
    float acc[4][4] = {};
#pragma unroll 8
    for (int kk = 0; kk < 128; ++kk) {
      const float4 a = *(const float4*)&Qs[kk][ty * 4];
      const float4 b = *(const float4*)&Ks[kk][tx * 4];
      const float avv[4] = {a.x, a.y, a.z, a.w};
      const float bvv[4] = {b.x, b.y, b.z, b.w};
#pragma unroll
      for (int e = 0; e < 4; ++e)
#pragma unroll
        for (int f = 0; f < 4; ++f) acc[e][f] += avv[e] * bvv[f];
    }
    float cs[4] = {0.f, 0.f, 0.f, 0.f};
#pragma unroll
    for (int e = 0; e < 4; ++e) {
      const int q = q0 + ty * 4 + e;
      const float ri = rinv[ty * 4 + e];
#pragma unroll
      for (int f = 0; f < 4; ++f) {
        const int j = j0 + tx * 4 + f;
        if (j <= q) {
          float s = acc[e][f] * SCALING;
          s = 50.0f * tanhf(s * 0.02f);
          cs[f] += __expf(s) * ri;
        }
      }
    }
    __syncthreads();   // red free for reuse
#pragma unroll
    for (int f = 0; f < 4; ++f) red[tx * 4 + f][ty] = cs[f];
    __syncthreads();
    if (tid < 64) {
      float v = 0.f;
#pragma unroll
      for (int y = 0; y < 16; ++y) v += red[tid][y];
      atomicAdd(&imp[j0 + tid], v);
    }
    __syncthreads();
  }
}

// ============================================================
// Kernel 4: top-k (k=1024) of importance[4096], sort indices ascending,
// append L-1 iff absent (reference's need_append), gather ids.
// Single block, bitonic sorts in LDS.
// ============================================================
__global__ __launch_bounds__(1024) void topk_kernel(
    const float* __restrict__ imp, const int* __restrict__ ids,
    int* __restrict__ out, int out_size) {
  __shared__ float v[L_SEQ];
  __shared__ int ix[L_SEQ];
  __shared__ int sel[K_SEL + 1];
  const int tid = threadIdx.x;
  for (int i = tid; i < L_SEQ; i += 1024) { v[i] = imp[i]; ix[i] = i; }
  __syncthreads();
  // bitonic sort descending by value
  for (int k = 2; k <= L_SEQ; k <<= 1) {
    for (int j = k >> 1; j > 0; j >>= 1) {
#pragma unroll 1
      for (int t = tid; t < L_SEQ / 2; t += 1024) {
        const int i = ((t & ~(j - 1)) << 1) | (t & (j - 1));
        const int l = i | j;
        const float vi = v[i], vl = v[l];
        const bool desc = ((i & k) == 0);
        if (desc ? (vi < vl) : (vi > vl)) {
          v[i] = vl; v[l] = vi;
          const int tmp = ix[i]; ix[i] = ix[l]; ix[l] = tmp;
        }
      }
      __syncthreads();
    }
  }
  sel[tid] = ix[tid];           // top-1024 indices (value-descending order)
  __syncthreads();
  // bitonic sort ascending by index
  for (int k = 2; k <= K_SEL; k <<= 1) {
    for (int j = k >> 1; j > 0; j >>= 1) {
      if (tid < K_SEL / 2) {
        const int i = ((tid & ~(j - 1)) << 1) | (tid & (j - 1));
        const int l = i | j;
        const int si = sel[i], sl = sel[l];
        const bool asc = ((i & k) == 0);
        if (asc ? (si > sl) : (si < sl)) { sel[i] = sl; sel[l] = si; }
      }
      __syncthreads();
    }
  }
  if (tid == 0) sel[K_SEL] = L_SEQ - 1;   // append slot (used iff absent)
  __syncthreads();
  const int half = out_size >> 1;         // k_sel (+1 if reference appended)
  for (int i = tid; i < half; i += 1024) {
    const int idx2 = (i < K_SEL) ? sel[i] : sel[K_SEL];
    out[half + i] = idx2;       // topk (second output)
    out[i] = ids[idx2];         // pruned_ids (first output)
  }
}

// ============================================================
extern "C" void kernel_launch(void* const* d_in, const int* in_sizes, int n_in,
                              void* d_out, int out_size, void* d_ws, size_t ws_size,
                              hipStream_t stream) {
  const int*   ids   = (const int*)d_in[0];
  const float* table = (const float*)d_in[1];
  const float* wq    = (const float*)d_in[2];
  const float* wk    = (const float*)d_in[3];
  char* ws = (char*)d_ws;
  float* Q   = (float*)ws;                               // 32 MB: [L][NQ*HD]
  float* K   = (float*)(ws + 32ull * 1024 * 1024);       // 16 MB: [L][NKV*HD]
  float* imp = (float*)(ws + 48ull * 1024 * 1024);       // 16 KB
  int* out = (int*)d_out;

  hipMemsetAsync(imp, 0, L_SEQ * sizeof(float), stream);

  dim3 blk(256);
  gemm_embed<<<dim3((NQ * HD) / 64, L_SEQ / 64), blk, 0, stream>>>(ids, table, wq, Q, NQ * HD);
  gemm_embed<<<dim3((NKV * HD) / 64, L_SEQ / 64), blk, 0, stream>>>(ids, table, wk, K, NKV * HD);
  rope_inplace<<<(L_SEQ * NQ * 64) / 256, blk, 0, stream>>>(Q, NQ, 4);
  rope_inplace<<<(L_SEQ * NKV * 64) / 256, blk, 0, stream>>>(K, NKV, 3);
  attn_stats<<<dim3(L_SEQ / 64, NQ), blk, 0, stream>>>(Q, K, imp);
  topk_kernel<<<1, 1024, 0, stream>>>(imp, ids, out, out_size);
}

// Round 2
// 1439.144 us; speedup vs baseline: 3.1081x; 3.1081x over previous
//
#include <hip/hip_runtime.h>
#include <hip/hip_bf16.h>
#include <math.h>

// ---------------- problem constants ----------------
#define L_SEQ   4096
#define D_MODEL 2048
#define NQ      16
#define NKV     8
#define HD      128
#define SCALING 0.08838834764831845f   // 128^-0.5
#define K_SEL   1024                   // L * 0.25

typedef __attribute__((ext_vector_type(8))) short bf16x8;
typedef __attribute__((ext_vector_type(4))) float f32x4;

__device__ __forceinline__ unsigned short f2bf(float f) {
  union { float f; unsigned u; } v; v.f = f;
  unsigned r = v.u + 0x7fffu + ((v.u >> 16) & 1u);   // RNE
  return (unsigned short)(r >> 16);
}
__device__ __forceinline__ float bf2f(unsigned short b) {
  union { unsigned u; float f; } v; v.u = ((unsigned)b) << 16;
  return v.f;
}

// ============================================================
// Kernel 1: C[M][N] = gather(embed_table, ids)[M][2048] @ W[2048][N]
// fp32 math, bf16 output. 64x64 tile, 256 threads, 4x4/thread, BK=16.
// ============================================================
__global__ __launch_bounds__(256) void gemm_embed(
    const int* __restrict__ ids, const float* __restrict__ table,
    const float* __restrict__ W, unsigned short* __restrict__ C, int N) {
  __shared__ float As[16][68];
  __shared__ float Bs[16][68];
  const int tid = threadIdx.x;
  const int tx = tid & 15, ty = tid >> 4;
  const int bm = blockIdx.y * 64, bn = blockIdx.x * 64;

  const int arow = tid >> 2;
  const int acol4 = (tid & 3) * 4;
  const long arowbase = (long)ids[bm + arow] * D_MODEL;
  const int kr = tid >> 4;
  const int cc = (tid & 15) * 4;

  float acc[4][4] = {};
  for (int k0 = 0; k0 < D_MODEL; k0 += 16) {
    float4 av = *(const float4*)(table + arowbase + k0 + acol4);
    As[acol4 + 0][arow] = av.x; As[acol4 + 1][arow] = av.y;
    As[acol4 + 2][arow] = av.z; As[acol4 + 3][arow] = av.w;
    float4 bv = *(const float4*)(W + (long)(k0 + kr) * N + bn + cc);
    Bs[kr][cc + 0] = bv.x; Bs[kr][cc + 1] = bv.y;
    Bs[kr][cc + 2] = bv.z; Bs[kr][cc + 3] = bv.w;
    __syncthreads();
#pragma unroll
    for (int kk = 0; kk < 16; ++kk) {
      const float4 a = *(const float4*)&As[kk][ty * 4];
      const float4 b = *(const float4*)&Bs[kk][tx * 4];
      const float avv[4] = {a.x, a.y, a.z, a.w};
      const float bvv[4] = {b.x, b.y, b.z, b.w};
#pragma unroll
      for (int e = 0; e < 4; ++e)
#pragma unroll
        for (int f = 0; f < 4; ++f) acc[e][f] += avv[e] * bvv[f];
    }
    __syncthreads();
  }
#pragma unroll
  for (int e = 0; e < 4; ++e) {
    ushort4 o;
    o.x = f2bf(acc[e][0]); o.y = f2bf(acc[e][1]);
    o.z = f2bf(acc[e][2]); o.w = f2bf(acc[e][3]);
    *(ushort4*)(C + (long)(bm + ty * 4 + e) * N + bn + tx * 4) = o;
  }
}

// ============================================================
// Kernel 2: RoPE in place on bf16 X[L][NH*128]; thread owns (i,h,t)+(i,h,t+64)
// ============================================================
__global__ void rope_bf16(unsigned short* __restrict__ X, int NH, int lognh) {
  const int g = blockIdx.x * blockDim.x + threadIdx.x;
  const int t = g & 63;
  const int h = (g >> 6) & (NH - 1);
  const int i = g >> (6 + lognh);
  const float e = (float)(2 * t) / 128.0f;
  const float invf = 1.0f / powf(10000.0f, e);
  const float ang = (float)i * invf;
  const float c = cosf(ang), s = sinf(ang);
  const long base = (long)i * (NH * HD) + h * HD + t;
  const float x1 = bf2f(X[base]), x2 = bf2f(X[base + 64]);
  X[base]      = f2bf(x1 * c - x2 * s);
  X[base + 64] = f2bf(x2 * c + x1 * s);
}

// ============================================================
// Kernel 3: MFMA causal softmax column-sum accumulation.
// Block = (64-row q tile, kv-head) covering 2 q heads (GQA reuse of K tile).
// Wave w owns q rows [w*16, w*16+16). Two passes over j tiles of 64:
//   pass 1: Z row sums (no max-sub: |s|~3e-4; guarded tanh softcap)
//   pass 2: accumulate exp(s)/Z into imp[j]
// A-frag layout: m=lane&15, k=quad*8+j (registers, loaded once from global).
// B-frags from LDS K tile (row pad 136 ushorts -> min-alias ds_read_b128).
// C layout: col=lane&15, row=quad*4+reg.
// ============================================================
__global__ __launch_bounds__(256) void attn_mfma(
    const unsigned short* __restrict__ Qb,  // [L][NQ*HD] bf16
    const unsigned short* __restrict__ Kb,  // [L][NKV*HD] bf16
    float* __restrict__ imp) {
  __shared__ __align__(16) unsigned short Ks[64 * 136];
  __shared__ float colacc[4][64];
  const int tid = threadIdx.x;
  const int w = tid >> 6, lane = tid & 63;
  const int quad = lane >> 4, lr = lane & 15;
  const int bx = (gridDim.x - 1) - blockIdx.x;   // heavy (large bx) first
  const int kvh = blockIdx.y;
  const int q0 = bx * 64;

  // ---- load A fragments (Q rows for this wave, both q heads) ----
  bf16x8 aq[2][4];
  {
    const long rowb = (long)(q0 + w * 16 + lr) * (NQ * HD);
#pragma unroll
    for (int hh = 0; hh < 2; ++hh)
#pragma unroll
      for (int m = 0; m < 4; ++m)
        aq[hh][m] = *(const bf16x8*)(Qb + rowb + (2 * kvh + hh) * HD + m * 32 + quad * 8);
  }

  float zp[2][4] = {};

  // ================= pass 1: row sums =================
  for (int t = 0; t <= bx; ++t) {
    const int j0 = t * 64;
#pragma unroll
    for (int it = 0; it < 4; ++it) {
      const int chunk = tid + it * 256;         // 1024 chunks of 16B
      const int row = chunk >> 4, c = chunk & 15;
      *(bf16x8*)(&Ks[row * 136 + c * 8]) =
          *(const bf16x8*)(Kb + (long)(j0 + row) * (NKV * HD) + kvh * HD + c * 8);
    }
    __syncthreads();
    const bool diag = (t == bx);
    const int nsub = diag ? (w + 1) : 4;
    for (int sub = 0; sub < nsub; ++sub) {
      bf16x8 bf[4];
#pragma unroll
      for (int m = 0; m < 4; ++m)
        bf[m] = *(const bf16x8*)(&Ks[(sub * 16 + lr) * 136 + m * 32 + quad * 8]);
#pragma unroll
      for (int hh = 0; hh < 2; ++hh) {
        f32x4 acc = {0.f, 0.f, 0.f, 0.f};
#pragma unroll
        for (int m = 0; m < 4; ++m)
          acc = __builtin_amdgcn_mfma_f32_16x16x32_bf16(aq[hh][m], bf[m], acc, 0, 0, 0);
#pragma unroll
        for (int r = 0; r < 4; ++r) {
          float s = acc[r] * SCALING;
          if (fabsf(s) > 0.5f) s = 50.0f * tanhf(s * 0.02f);  // never taken here
          float e = __expf(s);
          if (diag && sub == w && lr > quad * 4 + r) e = 0.0f;
          zp[hh][r] += e;
        }
      }
    }
    __syncthreads();
  }

  // reduce Z across the 16 columns of each quad; invert
  float rinv[2][4];
#pragma unroll
  for (int hh = 0; hh < 2; ++hh)
#pragma unroll
    for (int r = 0; r < 4; ++r) {
      float z = zp[hh][r];
      z += __shfl_xor(z, 1); z += __shfl_xor(z, 2);
      z += __shfl_xor(z, 4); z += __shfl_xor(z, 8);
      rinv[hh][r] = 1.0f / z;
    }

  // ================= pass 2: column sums =================
  for (int t = 0; t <= bx; ++t) {
    const int j0 = t * 64;
#pragma unroll
    for (int it = 0; it < 4; ++it) {
      const int chunk = tid + it * 256;
      const int row = chunk >> 4, c = chunk & 15;
      *(bf16x8*)(&Ks[row * 136 + c * 8]) =
          *(const bf16x8*)(Kb + (long)(j0 + row) * (NKV * HD) + kvh * HD + c * 8);
    }
    colacc[w][lane] = 0.0f;
    __syncthreads();
    const bool diag = (t == bx);
    const int nsub = diag ? (w + 1) : 4;
    for (int sub = 0; sub < nsub; ++sub) {
      bf16x8 bf[4];
#pragma unroll
      for (int m = 0; m < 4; ++m)
        bf[m] = *(const bf16x8*)(&Ks[(sub * 16 + lr) * 136 + m * 32 + quad * 8]);
      float csum = 0.0f;
#pragma unroll
      for (int hh = 0; hh < 2; ++hh) {
        f32x4 acc = {0.f, 0.f, 0.f, 0.f};
#pragma unroll
        for (int m = 0; m < 4; ++m)
          acc = __builtin_amdgcn_mfma_f32_16x16x32_bf16(aq[hh][m], bf[m], acc, 0, 0, 0);
#pragma unroll
        for (int r = 0; r < 4; ++r) {
          float s = acc[r] * SCALING;
          if (fabsf(s) > 0.5f) s = 50.0f * tanhf(s * 0.02f);
          float e = __expf(s);
          if (diag && sub == w && lr > quad * 4 + r) e = 0.0f;
          csum += e * rinv[hh][r];
        }
      }
      csum += __shfl_xor(csum, 16);
      csum += __shfl_xor(csum, 32);
      if (lane < 16) colacc[w][sub * 16 + lr] = csum;
    }
    __syncthreads();
    if (tid < 64)
      atomicAdd(&imp[j0 + tid],
                colacc[0][tid] + colacc[1][tid] + colacc[2][tid] + colacc[3][tid]);
    __syncthreads();   // protect colacc/Ks before next iteration rewrites
  }
}

// ============================================================
// Kernel 4: top-k (k=1024), sort indices ascending, append L-1, gather ids.
// ============================================================
__global__ __launch_bounds__(1024) void topk_kernel(
    const float* __restrict__ imp, const int* __restrict__ ids,
    int* __restrict__ out, int out_size) {
  __shared__ float v[L_SEQ];
  __shared__ int ix[L_SEQ];
  __shared__ int sel[K_SEL + 1];
  const int tid = threadIdx.x;
  for (int i = tid; i < L_SEQ; i += 1024) { v[i] = imp[i]; ix[i] = i; }
  __syncthreads();
  for (int k = 2; k <= L_SEQ; k <<= 1) {
    for (int j = k >> 1; j > 0; j >>= 1) {
#pragma unroll 1
      for (int t = tid; t < L_SEQ / 2; t += 1024) {
        const int i = ((t & ~(j - 1)) << 1) | (t & (j - 1));
        const int l = i | j;
        const float vi = v[i], vl = v[l];
        const bool desc = ((i & k) == 0);
        if (desc ? (vi < vl) : (vi > vl)) {
          v[i] = vl; v[l] = vi;
          const int tmp = ix[i]; ix[i] = ix[l]; ix[l] = tmp;
        }
      }
      __syncthreads();
    }
  }
  sel[tid] = ix[tid];
  __syncthreads();
  for (int k = 2; k <= K_SEL; k <<= 1) {
    for (int j = k >> 1; j > 0; j >>= 1) {
      if (tid < K_SEL / 2) {
        const int i = ((tid & ~(j - 1)) << 1) | (tid & (j - 1));
        const int l = i | j;
        const int si = sel[i], sl = sel[l];
        const bool asc = ((i & k) == 0);
        if (asc ? (si > sl) : (si < sl)) { sel[i] = sl; sel[l] = si; }
      }
      __syncthreads();
    }
  }
  if (tid == 0) sel[K_SEL] = L_SEQ - 1;
  __syncthreads();
  const int half = out_size >> 1;
  for (int i = tid; i < half; i += 1024) {
    const int idx2 = (i < K_SEL) ? sel[i] : sel[K_SEL];
    out[half + i] = idx2;
    out[i] = ids[idx2];
  }
}

// ============================================================
extern "C" void kernel_launch(void* const* d_in, const int* in_sizes, int n_in,
                              void* d_out, int out_size, void* d_ws, size_t ws_size,
                              hipStream_t stream) {
  const int*   ids   = (const int*)d_in[0];
  const float* table = (const float*)d_in[1];
  const float* wq    = (const float*)d_in[2];
  const float* wk    = (const float*)d_in[3];
  char* ws = (char*)d_ws;
  unsigned short* Qb = (unsigned short*)ws;                          // 16 MB bf16 [L][2048]
  unsigned short* Kb = (unsigned short*)(ws + 16ull * 1024 * 1024);  //  8 MB bf16 [L][1024]
  float* imp = (float*)(ws + 24ull * 1024 * 1024);                   // 16 KB
  int* out = (int*)d_out;

  hipMemsetAsync(imp, 0, L_SEQ * sizeof(float), stream);

  dim3 blk(256);
  gemm_embed<<<dim3((NQ * HD) / 64, L_SEQ / 64), blk, 0, stream>>>(ids, table, wq, Qb, NQ * HD);
  gemm_embed<<<dim3((NKV * HD) / 64, L_SEQ / 64), blk, 0, stream>>>(ids, table, wk, Kb, NKV * HD);
  rope_bf16<<<(L_SEQ * NQ * 64) / 256, blk, 0, stream>>>(Qb, NQ, 4);
  rope_bf16<<<(L_SEQ * NKV * 64) / 256, blk, 0, stream>>>(Kb, NKV, 3);
  attn_mfma<<<dim3(L_SEQ / 64, NKV), blk, 0, stream>>>(Qb, Kb, imp);
  topk_kernel<<<1, 1024, 0, stream>>>(imp, ids, out, out_size);
}

// Round 3
// 892.061 us; speedup vs baseline: 5.0143x; 1.6133x over previous
//
#include <hip/hip_runtime.h>
#include <hip/hip_bf16.h>
#include <math.h>

// ---------------- problem constants ----------------
#define L_SEQ   4096
#define D_MODEL 2048
#define NQ      16
#define NKV     8
#define HD      128
#define CSTR    3072                   // combined QK row stride (NQ*HD + NKV*HD)
#define SCALING 0.08838834764831845f   // 128^-0.5
#define K_SEL   1024                   // L * 0.25

typedef __attribute__((ext_vector_type(8))) short bf16x8;
typedef __attribute__((ext_vector_type(4))) float f32x4;

__device__ __forceinline__ unsigned short f2bf(float f) {
  union { float f; unsigned u; } v; v.f = f;
  unsigned r = v.u + 0x7fffu + ((v.u >> 16) & 1u);   // RNE
  return (unsigned short)(r >> 16);
}
// pack two floats -> two bf16 (truncation; 0.4% rel noise, harmless for ranking)
__device__ __forceinline__ unsigned pk2(float a, float b) {
  return (__float_as_uint(b) & 0xffff0000u) | (__float_as_uint(a) >> 16);
}
__device__ __forceinline__ float bf2f(unsigned short b) {
  union { unsigned u; float f; } v; v.u = ((unsigned)b) << 16;
  return v.f;
}

typedef __attribute__((address_space(3))) unsigned int lds_u32;
typedef const __attribute__((address_space(1))) unsigned int glob_u32;
__device__ __forceinline__ void gl2lds16(const unsigned short* g, unsigned short* l) {
  __builtin_amdgcn_global_load_lds((glob_u32*)g, (lds_u32*)l, 16, 0, 0);
}

// ============================================================
// Kernel 1: Wt[3072][2048] bf16 = transpose([wq | wk]), k-contiguous rows.
// 64x64 tiles through LDS.
// ============================================================
__global__ __launch_bounds__(256) void prep_w(
    const float* __restrict__ wq, const float* __restrict__ wk,
    unsigned short* __restrict__ Wt) {
  __shared__ __align__(16) unsigned short T[64][80];  // 160B rows: 16B-aligned, odd dword stride
  const int tid = threadIdx.x;
  const int nt = blockIdx.x;      // 48 n-tiles
  const int kt = blockIdx.y;      // 32 k-tiles
  const float* src; int srcN, n0;
  if (nt < 32) { src = wq; srcN = 2048; n0 = nt * 64; }
  else         { src = wk; srcN = 1024; n0 = (nt - 32) * 64; }
  const int k0 = kt * 64;
#pragma unroll
  for (int p = 0; p < 4; ++p) {
    const int idx = p * 256 + tid;          // 1024 float4 slots
    const int row = idx >> 4;               // k 0..63
    const int c4 = (idx & 15) * 4;          // n 0..60
    float4 v = *(const float4*)(src + (size_t)(k0 + row) * srcN + n0 + c4);
    T[c4 + 0][row] = f2bf(v.x); T[c4 + 1][row] = f2bf(v.y);
    T[c4 + 2][row] = f2bf(v.z); T[c4 + 3][row] = f2bf(v.w);
  }
  __syncthreads();
#pragma unroll
  for (int p = 0; p < 2; ++p) {
    const int c = p * 256 + tid;            // 512 chunks of 8
    const int n = c >> 3, k8 = (c & 7) * 8;
    *(uint4*)(Wt + (size_t)(nt * 64 + n) * D_MODEL + k0 + k8) = *(const uint4*)(&T[n][k8]);
  }
}

// ============================================================
// Kernel 2: C[4096][3072] bf16 = gather(table, ids) @ [wq|wk], MFMA bf16.
// 128x128 tile, BK=32, 256 threads (4 waves, 2x2 of 64x64).
// B staged async via global_load_lds (Wt is k-contiguous);
// A staged manually: gather fp32 -> trunc-pack bf16 -> ds_write_b128.
// ============================================================
__global__ __launch_bounds__(256) void gemm_qk(
    const int* __restrict__ ids, const float* __restrict__ table,
    const unsigned short* __restrict__ Wt, unsigned short* __restrict__ C) {
  __shared__ __align__(16) unsigned short As[128 * 32];
  __shared__ __align__(16) unsigned short Bs[128 * 32];
  const int tid = threadIdx.x;
  const int w = tid >> 6, lane = tid & 63;
  const int quad = lane >> 4, lr = lane & 15;
  const int m0 = blockIdx.y * 128, n0 = blockIdx.x * 128;
  const int wm = (w >> 1) * 64, wn = (w & 1) * 64;

  // manual A: thread owns (row = tid>>1, half = tid&1) every iteration
  const int arow = tid >> 1, ahalf = tid & 1;
  const float* aptr = table + (size_t)ids[m0 + arow] * D_MODEL + ahalf * 16;
  unsigned short* asl = &As[arow * 32 + ahalf * 16];

  // async B: wave w covers tile rows [w*16, w*16+16) and [64+w*16, ...)
  const unsigned short* bptr =
      Wt + (size_t)(n0 + w * 16 + (lane >> 2)) * D_MODEL + (lane & 3) * 8;
  unsigned short* bsl0 = &Bs[(w * 16) * 32];
  unsigned short* bsl1 = &Bs[(64 + w * 16) * 32];

  f32x4 acc[4][4];
#pragma unroll
  for (int i = 0; i < 4; ++i)
#pragma unroll
    for (int j = 0; j < 4; ++j) acc[i][j] = (f32x4){0.f, 0.f, 0.f, 0.f};

  for (int k0 = 0; k0 < D_MODEL; k0 += 32) {
    __syncthreads();                         // LDS free (prev compute done)
    gl2lds16(bptr + k0, bsl0);
    gl2lds16(bptr + 64 * D_MODEL + k0, bsl1);
    const float4 f0 = *(const float4*)(aptr + k0);
    const float4 f1 = *(const float4*)(aptr + k0 + 4);
    const float4 f2 = *(const float4*)(aptr + k0 + 8);
    const float4 f3 = *(const float4*)(aptr + k0 + 12);
    uint4 u0, u1;
    u0.x = pk2(f0.x, f0.y); u0.y = pk2(f0.z, f0.w);
    u0.z = pk2(f1.x, f1.y); u0.w = pk2(f1.z, f1.w);
    u1.x = pk2(f2.x, f2.y); u1.y = pk2(f2.z, f2.w);
    u1.z = pk2(f3.x, f3.y); u1.w = pk2(f3.z, f3.w);
    *(uint4*)(asl) = u0;
    *(uint4*)(asl + 8) = u1;
    __syncthreads();                         // staging (vm + lds) drained
    bf16x8 af[4], bf[4];
#pragma unroll
    for (int mt = 0; mt < 4; ++mt)
      af[mt] = *(const bf16x8*)&As[(wm + mt * 16 + lr) * 32 + quad * 8];
#pragma unroll
    for (int nt = 0; nt < 4; ++nt)
      bf[nt] = *(const bf16x8*)&Bs[(wn + nt * 16 + lr) * 32 + quad * 8];
#pragma unroll
    for (int mt = 0; mt < 4; ++mt)
#pragma unroll
      for (int nt = 0; nt < 4; ++nt)
        acc[mt][nt] = __builtin_amdgcn_mfma_f32_16x16x32_bf16(af[mt], bf[nt], acc[mt][nt], 0, 0, 0);
  }
#pragma unroll
  for (int mt = 0; mt < 4; ++mt) {
    const int row = m0 + wm + mt * 16 + quad * 4;
#pragma unroll
    for (int nt = 0; nt < 4; ++nt) {
      const int col = n0 + wn + nt * 16 + lr;
#pragma unroll
      for (int r = 0; r < 4; ++r)
        C[(size_t)(row + r) * CSTR + col] = f2bf(acc[mt][nt][r]);
    }
  }
}

// ============================================================
// Kernel 3: RoPE in place on combined C[4096][3072] (24 heads of 128)
// ============================================================
__global__ void rope_all(unsigned short* __restrict__ C) {
  const int g = blockIdx.x * blockDim.x + threadIdx.x;
  const int t = g & 63;
  const int hi = g >> 6;           // i*24 + h
  const int h = hi % 24;
  const int i = hi / 24;
  const float e = (float)(2 * t) / 128.0f;
  const float invf = 1.0f / powf(10000.0f, e);
  const float ang = (float)i * invf;
  const float c = cosf(ang), s = sinf(ang);
  const size_t base = (size_t)i * CSTR + h * HD + t;
  const float x1 = bf2f(C[base]), x2 = bf2f(C[base + 64]);
  C[base]      = f2bf(x1 * c - x2 * s);
  C[base + 64] = f2bf(x2 * c + x1 * s);
}

// ============================================================
// Kernel 4: MFMA causal softmax column-sum accumulation (round-2 design,
// strides updated for the combined QK buffer).
// ============================================================
__global__ __launch_bounds__(256) void attn_mfma(
    const unsigned short* __restrict__ Qb,  // [L][CSTR] bf16, cols 0..2047
    const unsigned short* __restrict__ Kb,  // = Qb + 2048, cols 0..1023
    float* __restrict__ imp) {
  __shared__ __align__(16) unsigned short Ks[64 * 136];
  __shared__ float colacc[4][64];
  const int tid = threadIdx.x;
  const int w = tid >> 6, lane = tid & 63;
  const int quad = lane >> 4, lr = lane & 15;
  const int bx = (gridDim.x - 1) - blockIdx.x;   // heavy (large bx) first
  const int kvh = blockIdx.y;
  const int q0 = bx * 64;

  bf16x8 aq[2][4];
  {
    const size_t rowb = (size_t)(q0 + w * 16 + lr) * CSTR;
#pragma unroll
    for (int hh = 0; hh < 2; ++hh)
#pragma unroll
      for (int m = 0; m < 4; ++m)
        aq[hh][m] = *(const bf16x8*)(Qb + rowb + (2 * kvh + hh) * HD + m * 32 + quad * 8);
  }

  float zp[2][4] = {};

  // ---- pass 1: row sums ----
  for (int t = 0; t <= bx; ++t) {
    const int j0 = t * 64;
#pragma unroll
    for (int it = 0; it < 4; ++it) {
      const int chunk = tid + it * 256;
      const int row = chunk >> 4, c = chunk & 15;
      *(bf16x8*)(&Ks[row * 136 + c * 8]) =
          *(const bf16x8*)(Kb + (size_t)(j0 + row) * CSTR + kvh * HD + c * 8);
    }
    __syncthreads();
    const bool diag = (t == bx);
    const int nsub = diag ? (w + 1) : 4;
    for (int sub = 0; sub < nsub; ++sub) {
      bf16x8 bf[4];
#pragma unroll
      for (int m = 0; m < 4; ++m)
        bf[m] = *(const bf16x8*)(&Ks[(sub * 16 + lr) * 136 + m * 32 + quad * 8]);
#pragma unroll
      for (int hh = 0; hh < 2; ++hh) {
        f32x4 acc = {0.f, 0.f, 0.f, 0.f};
#pragma unroll
        for (int m = 0; m < 4; ++m)
          acc = __builtin_amdgcn_mfma_f32_16x16x32_bf16(aq[hh][m], bf[m], acc, 0, 0, 0);
#pragma unroll
        for (int r = 0; r < 4; ++r) {
          float s = acc[r] * SCALING;
          if (fabsf(s) > 0.5f) s = 50.0f * tanhf(s * 0.02f);
          float e = __expf(s);
          if (diag && sub == w && lr > quad * 4 + r) e = 0.0f;
          zp[hh][r] += e;
        }
      }
    }
    __syncthreads();
  }

  float rinv[2][4];
#pragma unroll
  for (int hh = 0; hh < 2; ++hh)
#pragma unroll
    for (int r = 0; r < 4; ++r) {
      float z = zp[hh][r];
      z += __shfl_xor(z, 1); z += __shfl_xor(z, 2);
      z += __shfl_xor(z, 4); z += __shfl_xor(z, 8);
      rinv[hh][r] = 1.0f / z;
    }

  // ---- pass 2: column sums ----
  for (int t = 0; t <= bx; ++t) {
    const int j0 = t * 64;
#pragma unroll
    for (int it = 0; it < 4; ++it) {
      const int chunk = tid + it * 256;
      const int row = chunk >> 4, c = chunk & 15;
      *(bf16x8*)(&Ks[row * 136 + c * 8]) =
          *(const bf16x8*)(Kb + (size_t)(j0 + row) * CSTR + kvh * HD + c * 8);
    }
    colacc[w][lane] = 0.0f;
    __syncthreads();
    const bool diag = (t == bx);
    const int nsub = diag ? (w + 1) : 4;
    for (int sub = 0; sub < nsub; ++sub) {
      bf16x8 bf[4];
#pragma unroll
      for (int m = 0; m < 4; ++m)
        bf[m] = *(const bf16x8*)(&Ks[(sub * 16 + lr) * 136 + m * 32 + quad * 8]);
      float csum = 0.0f;
#pragma unroll
      for (int hh = 0; hh < 2; ++hh) {
        f32x4 acc = {0.f, 0.f, 0.f, 0.f};
#pragma unroll
        for (int m = 0; m < 4; ++m)
          acc = __builtin_amdgcn_mfma_f32_16x16x32_bf16(aq[hh][m], bf[m], acc, 0, 0, 0);
#pragma unroll
        for (int r = 0; r < 4; ++r) {
          float s = acc[r] * SCALING;
          if (fabsf(s) > 0.5f) s = 50.0f * tanhf(s * 0.02f);
          float e = __expf(s);
          if (diag && sub == w && lr > quad * 4 + r) e = 0.0f;
          csum += e * rinv[hh][r];
        }
      }
      csum += __shfl_xor(csum, 16);
      csum += __shfl_xor(csum, 32);
      if (lane < 16) colacc[w][sub * 16 + lr] = csum;
    }
    __syncthreads();
    if (tid < 64)
      atomicAdd(&imp[j0 + tid],
                colacc[0][tid] + colacc[1][tid] + colacc[2][tid] + colacc[3][tid]);
    __syncthreads();
  }
}

// ============================================================
// Kernel 5: top-k (k=1024), sort indices ascending, append L-1, gather ids.
// ============================================================
__global__ __launch_bounds__(1024) void topk_kernel(
    const float* __restrict__ imp, const int* __restrict__ ids,
    int* __restrict__ out, int out_size) {
  __shared__ float v[L_SEQ];
  __shared__ int ix[L_SEQ];
  __shared__ int sel[K_SEL + 1];
  const int tid = threadIdx.x;
  for (int i = tid; i < L_SEQ; i += 1024) { v[i] = imp[i]; ix[i] = i; }
  __syncthreads();
  for (int k = 2; k <= L_SEQ; k <<= 1) {
    for (int j = k >> 1; j > 0; j >>= 1) {
#pragma unroll 1
      for (int t = tid; t < L_SEQ / 2; t += 1024) {
        const int i = ((t & ~(j - 1)) << 1) | (t & (j - 1));
        const int l = i | j;
        const float vi = v[i], vl = v[l];
        const bool desc = ((i & k) == 0);
        if (desc ? (vi < vl) : (vi > vl)) {
          v[i] = vl; v[l] = vi;
          const int tmp = ix[i]; ix[i] = ix[l]; ix[l] = tmp;
        }
      }
      __syncthreads();
    }
  }
  sel[tid] = ix[tid];
  __syncthreads();
  for (int k = 2; k <= K_SEL; k <<= 1) {
    for (int j = k >> 1; j > 0; j >>= 1) {
      if (tid < K_SEL / 2) {
        const int i = ((tid & ~(j - 1)) << 1) | (tid & (j - 1));
        const int l = i | j;
        const int si = sel[i], sl = sel[l];
        const bool asc = ((i & k) == 0);
        if (asc ? (si > sl) : (si < sl)) { sel[i] = sl; sel[l] = si; }
      }
      __syncthreads();
    }
  }
  if (tid == 0) sel[K_SEL] = L_SEQ - 1;
  __syncthreads();
  const int half = out_size >> 1;
  for (int i = tid; i < half; i += 1024) {
    const int idx2 = (i < K_SEL) ? sel[i] : sel[K_SEL];
    out[half + i] = idx2;
    out[i] = ids[idx2];
  }
}

// ============================================================
extern "C" void kernel_launch(void* const* d_in, const int* in_sizes, int n_in,
                              void* d_out, int out_size, void* d_ws, size_t ws_size,
                              hipStream_t stream) {
  const int*   ids   = (const int*)d_in[0];
  const float* table = (const float*)d_in[1];
  const float* wq    = (const float*)d_in[2];
  const float* wk    = (const float*)d_in[3];
  char* ws = (char*)d_ws;
  unsigned short* Wt = (unsigned short*)ws;                          // 12 MB [3072][2048]
  unsigned short* C  = (unsigned short*)(ws + 12ull * 1024 * 1024);  // 24 MB [4096][3072]
  float* imp = (float*)(ws + 36ull * 1024 * 1024);                   // 16 KB
  int* out = (int*)d_out;

  hipMemsetAsync(imp, 0, L_SEQ * sizeof(float), stream);

  dim3 blk(256);
  prep_w<<<dim3(48, 32), blk, 0, stream>>>(wq, wk, Wt);
  gemm_qk<<<dim3(CSTR / 128, L_SEQ / 128), blk, 0, stream>>>(ids, table, Wt, C);
  rope_all<<<(L_SEQ * 24 * 64) / 256, blk, 0, stream>>>(C);
  attn_mfma<<<dim3(L_SEQ / 64, NKV), blk, 0, stream>>>(C, C + 2048, imp);
  topk_kernel<<<1, 1024, 0, stream>>>(imp, ids, out, out_size);
}

// Round 4
// 737.612 us; speedup vs baseline: 6.0642x; 1.2094x over previous
//
#include <hip/hip_runtime.h>
#include <hip/hip_bf16.h>
#include <math.h>

// ---------------- problem constants ----------------
#define L_SEQ   4096
#define D_MODEL 2048
#define NQ      16
#define NKV     8
#define HD      128
#define CSTR    3072                   // combined QK row stride (NQ*HD + NKV*HD)
#define SCALING 0.08838834764831845f   // 128^-0.5
#define LOG2E   1.4426950408889634f
#define K_SEL   1024                   // L * 0.25
#define CHUNK   8                      // j-tiles per attn block
#define NCHUNK  288                    // sum_{b=0..63} ceil((b+1)/8)

typedef __attribute__((ext_vector_type(8))) short bf16x8;
typedef __attribute__((ext_vector_type(4))) float f32x4;

__device__ __forceinline__ unsigned short f2bf(float f) {
  union { float f; unsigned u; } v; v.f = f;
  unsigned r = v.u + 0x7fffu + ((v.u >> 16) & 1u);   // RNE
  return (unsigned short)(r >> 16);
}
__device__ __forceinline__ unsigned pk2(float a, float b) {
  return (__float_as_uint(b) & 0xffff0000u) | (__float_as_uint(a) >> 16);
}
__device__ __forceinline__ float bf2f(unsigned short b) {
  union { unsigned u; float f; } v; v.u = ((unsigned)b) << 16;
  return v.f;
}

typedef __attribute__((address_space(3))) unsigned int lds_u32;
typedef const __attribute__((address_space(1))) unsigned int glob_u32;
__device__ __forceinline__ void gl2lds16(const unsigned short* g, unsigned short* l) {
  __builtin_amdgcn_global_load_lds((glob_u32*)g, (lds_u32*)l, 16, 0, 0);
}

// ============================================================
// Kernel 1: Wt[3072][2048] bf16 = transpose([wq | wk]), k-contiguous rows.
// ============================================================
__global__ __launch_bounds__(256) void prep_w(
    const float* __restrict__ wq, const float* __restrict__ wk,
    unsigned short* __restrict__ Wt) {
  __shared__ __align__(16) unsigned short T[64][80];
  const int tid = threadIdx.x;
  const int nt = blockIdx.x;      // 48 n-tiles
  const int kt = blockIdx.y;      // 32 k-tiles
  const float* src; int srcN, n0;
  if (nt < 32) { src = wq; srcN = 2048; n0 = nt * 64; }
  else         { src = wk; srcN = 1024; n0 = (nt - 32) * 64; }
  const int k0 = kt * 64;
#pragma unroll
  for (int p = 0; p < 4; ++p) {
    const int idx = p * 256 + tid;
    const int row = idx >> 4;
    const int c4 = (idx & 15) * 4;
    float4 v = *(const float4*)(src + (size_t)(k0 + row) * srcN + n0 + c4);
    T[c4 + 0][row] = f2bf(v.x); T[c4 + 1][row] = f2bf(v.y);
    T[c4 + 2][row] = f2bf(v.z); T[c4 + 3][row] = f2bf(v.w);
  }
  __syncthreads();
#pragma unroll
  for (int p = 0; p < 2; ++p) {
    const int c = p * 256 + tid;
    const int n = c >> 3, k8 = (c & 7) * 8;
    *(uint4*)(Wt + (size_t)(nt * 64 + n) * D_MODEL + k0 + k8) = *(const uint4*)(&T[n][k8]);
  }
}

// ============================================================
// Kernel 2: C[4096][3072] bf16 = gather(table, ids) @ [wq|wk], MFMA bf16.
// ============================================================
__global__ __launch_bounds__(256) void gemm_qk(
    const int* __restrict__ ids, const float* __restrict__ table,
    const unsigned short* __restrict__ Wt, unsigned short* __restrict__ C) {
  __shared__ __align__(16) unsigned short As[128 * 32];
  __shared__ __align__(16) unsigned short Bs[128 * 32];
  const int tid = threadIdx.x;
  const int w = tid >> 6, lane = tid & 63;
  const int quad = lane >> 4, lr = lane & 15;
  const int m0 = blockIdx.y * 128, n0 = blockIdx.x * 128;
  const int wm = (w >> 1) * 64, wn = (w & 1) * 64;

  const int arow = tid >> 1, ahalf = tid & 1;
  const float* aptr = table + (size_t)ids[m0 + arow] * D_MODEL + ahalf * 16;
  unsigned short* asl = &As[arow * 32 + ahalf * 16];

  const unsigned short* bptr =
      Wt + (size_t)(n0 + w * 16 + (lane >> 2)) * D_MODEL + (lane & 3) * 8;
  unsigned short* bsl0 = &Bs[(w * 16) * 32];
  unsigned short* bsl1 = &Bs[(64 + w * 16) * 32];

  f32x4 acc[4][4];
#pragma unroll
  for (int i = 0; i < 4; ++i)
#pragma unroll
    for (int j = 0; j < 4; ++j) acc[i][j] = (f32x4){0.f, 0.f, 0.f, 0.f};

  for (int k0 = 0; k0 < D_MODEL; k0 += 32) {
    __syncthreads();
    gl2lds16(bptr + k0, bsl0);
    gl2lds16(bptr + 64 * D_MODEL + k0, bsl1);
    const float4 f0 = *(const float4*)(aptr + k0);
    const float4 f1 = *(const float4*)(aptr + k0 + 4);
    const float4 f2 = *(const float4*)(aptr + k0 + 8);
    const float4 f3 = *(const float4*)(aptr + k0 + 12);
    uint4 u0, u1;
    u0.x = pk2(f0.x, f0.y); u0.y = pk2(f0.z, f0.w);
    u0.z = pk2(f1.x, f1.y); u0.w = pk2(f1.z, f1.w);
    u1.x = pk2(f2.x, f2.y); u1.y = pk2(f2.z, f2.w);
    u1.z = pk2(f3.x, f3.y); u1.w = pk2(f3.z, f3.w);
    *(uint4*)(asl) = u0;
    *(uint4*)(asl + 8) = u1;
    __syncthreads();
    bf16x8 af[4], bfr[4];
#pragma unroll
    for (int mt = 0; mt < 4; ++mt)
      af[mt] = *(const bf16x8*)&As[(wm + mt * 16 + lr) * 32 + quad * 8];
#pragma unroll
    for (int nt = 0; nt < 4; ++nt)
      bfr[nt] = *(const bf16x8*)&Bs[(wn + nt * 16 + lr) * 32 + quad * 8];
#pragma unroll
    for (int mt = 0; mt < 4; ++mt)
#pragma unroll
      for (int nt = 0; nt < 4; ++nt)
        acc[mt][nt] = __builtin_amdgcn_mfma_f32_16x16x32_bf16(af[mt], bfr[nt], acc[mt][nt], 0, 0, 0);
  }
#pragma unroll
  for (int mt = 0; mt < 4; ++mt) {
    const int row = m0 + wm + mt * 16 + quad * 4;
#pragma unroll
    for (int nt = 0; nt < 4; ++nt) {
      const int col = n0 + wn + nt * 16 + lr;
#pragma unroll
      for (int r = 0; r < 4; ++r)
        C[(size_t)(row + r) * CSTR + col] = f2bf(acc[mt][nt][r]);
    }
  }
}

// ============================================================
// Kernel 3: RoPE in place on combined C[4096][3072]
// ============================================================
__global__ void rope_all(unsigned short* __restrict__ C) {
  const int g = blockIdx.x * blockDim.x + threadIdx.x;
  const int t = g & 63;
  const int hi = g >> 6;
  const int h = hi % 24;
  const int i = hi / 24;
  const float e = (float)(2 * t) / 128.0f;
  const float invf = 1.0f / powf(10000.0f, e);
  const float ang = (float)i * invf;
  const float c = cosf(ang), s = sinf(ang);
  const size_t base = (size_t)i * CSTR + h * HD + t;
  const float x1 = bf2f(C[base]), x2 = bf2f(C[base + 64]);
  C[base]      = f2bf(x1 * c - x2 * s);
  C[base + 64] = f2bf(x2 * c + x1 * s);
}

// ============================================================
// Shared mapping: blockIdx.x (0..NCHUNK-1) -> (bx, chunk), heavy bx first.
// ============================================================
__device__ __forceinline__ void chunk_map(int bidx, int& bx, int& ch) {
  int rem = bidx;
  for (int b = 63; b >= 0; --b) {
    const int nc = (b + 2 + CHUNK - 1) >> 3;   // ceil((b+1)/8)
    if (rem < nc) { bx = b; ch = rem; return; }
    rem -= nc;
  }
  bx = 0; ch = 0;
}

// ============================================================
// Kernel 4a: row-denominator partials. Block = (chunk of <=8 j-tiles, kvh).
// atomicAdd partial sums into Z[16][4096].
// ============================================================
__global__ __launch_bounds__(256) void attn_z(
    const unsigned short* __restrict__ Qb,  // [L][CSTR], q heads at col 0
    const unsigned short* __restrict__ Kb,  // = Qb + 2048
    float* __restrict__ Z) {
  __shared__ __align__(16) unsigned short Ks[64 * 136];
  const int tid = threadIdx.x;
  const int w = tid >> 6, lane = tid & 63;
  const int quad = lane >> 4, lr = lane & 15;
  const int kvh = blockIdx.y;
  int bx, ch; chunk_map(blockIdx.x, bx, ch);
  const int q0 = bx * 64;
  const int t1 = min(ch * CHUNK + CHUNK, bx + 1);

  bf16x8 aq[2][4];
  const size_t rowb = (size_t)(q0 + w * 16 + lr) * CSTR;
#pragma unroll
  for (int hh = 0; hh < 2; ++hh)
#pragma unroll
    for (int m = 0; m < 4; ++m)
      aq[hh][m] = *(const bf16x8*)(Qb + rowb + (2 * kvh + hh) * HD + m * 32 + quad * 8);

  float zp[2][4] = {};
  for (int t = ch * CHUNK; t < t1; ++t) {
    const int j0 = t * 64;
#pragma unroll
    for (int it = 0; it < 4; ++it) {
      const int c = tid + it * 256;
      const int row = c >> 4, cc = c & 15;
      *(bf16x8*)(&Ks[row * 136 + cc * 8]) =
          *(const bf16x8*)(Kb + (size_t)(j0 + row) * CSTR + kvh * HD + cc * 8);
    }
    __syncthreads();
    const bool diag = (t == bx);
    const int nsub = diag ? (w + 1) : 4;
    for (int sub = 0; sub < nsub; ++sub) {
      bf16x8 bfr[4];
#pragma unroll
      for (int m = 0; m < 4; ++m)
        bfr[m] = *(const bf16x8*)(&Ks[(sub * 16 + lr) * 136 + m * 32 + quad * 8]);
      const bool masked = diag && (sub == w);
#pragma unroll
      for (int hh = 0; hh < 2; ++hh) {
        f32x4 acc = {0.f, 0.f, 0.f, 0.f};
#pragma unroll
        for (int m = 0; m < 4; ++m)
          acc = __builtin_amdgcn_mfma_f32_16x16x32_bf16(aq[hh][m], bfr[m], acc, 0, 0, 0);
#pragma unroll
        for (int r = 0; r < 4; ++r) {
          const float a = acc[r];
          float sc = a * (SCALING * LOG2E);
          if (__builtin_expect(fabsf(a) > 5.65685424949238f, 0))
            sc = 50.0f * tanhf(a * (SCALING * 0.02f)) * LOG2E;  // softcap (never taken)
          float e = exp2f(sc);
          if (masked && lr > quad * 4 + r) e = 0.0f;
          zp[hh][r] += e;
        }
      }
    }
    __syncthreads();
  }
#pragma unroll
  for (int hh = 0; hh < 2; ++hh)
#pragma unroll
    for (int r = 0; r < 4; ++r) {
      float z = zp[hh][r];
      z += __shfl_xor(z, 1); z += __shfl_xor(z, 2);
      z += __shfl_xor(z, 4); z += __shfl_xor(z, 8);
      if (lr == 0)
        atomicAdd(&Z[(size_t)(2 * kvh + hh) * L_SEQ + q0 + w * 16 + quad * 4 + r], z);
    }
}

// ============================================================
// Kernel 4b: column sums. Same chunking; epilogue = fma + exp2 + add.
// ============================================================
__global__ __launch_bounds__(256) void attn_col(
    const unsigned short* __restrict__ Qb,
    const unsigned short* __restrict__ Kb,
    const float* __restrict__ Z, float* __restrict__ imp) {
  __shared__ __align__(16) unsigned short Ks[64 * 136];
  const int tid = threadIdx.x;
  const int w = tid >> 6, lane = tid & 63;
  const int quad = lane >> 4, lr = lane & 15;
  const int kvh = blockIdx.y;
  int bx, ch; chunk_map(blockIdx.x, bx, ch);
  const int q0 = bx * 64;
  const int t1 = min(ch * CHUNK + CHUNK, bx + 1);

  bf16x8 aq[2][4];
  const size_t rowb = (size_t)(q0 + w * 16 + lr) * CSTR;
#pragma unroll
  for (int hh = 0; hh < 2; ++hh)
#pragma unroll
    for (int m = 0; m < 4; ++m)
      aq[hh][m] = *(const bf16x8*)(Qb + rowb + (2 * kvh + hh) * HD + m * 32 + quad * 8);

  float l2r[2][4];
#pragma unroll
  for (int hh = 0; hh < 2; ++hh)
#pragma unroll
    for (int r = 0; r < 4; ++r)
      l2r[hh][r] = -__log2f(Z[(size_t)(2 * kvh + hh) * L_SEQ + q0 + w * 16 + quad * 4 + r]);

  for (int t = ch * CHUNK; t < t1; ++t) {
    const int j0 = t * 64;
#pragma unroll
    for (int it = 0; it < 4; ++it) {
      const int c = tid + it * 256;
      const int row = c >> 4, cc = c & 15;
      *(bf16x8*)(&Ks[row * 136 + cc * 8]) =
          *(const bf16x8*)(Kb + (size_t)(j0 + row) * CSTR + kvh * HD + cc * 8);
    }
    __syncthreads();
    const bool diag = (t == bx);
    const int nsub = diag ? (w + 1) : 4;
    for (int sub = 0; sub < nsub; ++sub) {
      bf16x8 bfr[4];
#pragma unroll
      for (int m = 0; m < 4; ++m)
        bfr[m] = *(const bf16x8*)(&Ks[(sub * 16 + lr) * 136 + m * 32 + quad * 8]);
      const bool masked = diag && (sub == w);
      float csum = 0.0f;
#pragma unroll
      for (int hh = 0; hh < 2; ++hh) {
        f32x4 acc = {0.f, 0.f, 0.f, 0.f};
#pragma unroll
        for (int m = 0; m < 4; ++m)
          acc = __builtin_amdgcn_mfma_f32_16x16x32_bf16(aq[hh][m], bfr[m], acc, 0, 0, 0);
#pragma unroll
        for (int r = 0; r < 4; ++r) {
          const float a = acc[r];
          float sc = __builtin_fmaf(a, SCALING * LOG2E, l2r[hh][r]);
          if (__builtin_expect(fabsf(a) > 5.65685424949238f, 0))
            sc = __builtin_fmaf(50.0f * tanhf(a * (SCALING * 0.02f)), LOG2E, l2r[hh][r]);
          float e = exp2f(sc);
          if (masked && lr > quad * 4 + r) e = 0.0f;
          csum += e;
        }
      }
      csum += __shfl_xor(csum, 16);
      csum += __shfl_xor(csum, 32);
      if (lane < 16) atomicAdd(&imp[j0 + sub * 16 + lr], csum);
    }
    __syncthreads();
  }
}

// ============================================================
// Kernel 5: top-k (k=1024), sort indices ascending, append L-1, gather ids.
// ============================================================
__global__ __launch_bounds__(1024) void topk_kernel(
    const float* __restrict__ imp, const int* __restrict__ ids,
    int* __restrict__ out, int out_size) {
  __shared__ float v[L_SEQ];
  __shared__ int ix[L_SEQ];
  __shared__ int sel[K_SEL + 1];
  const int tid = threadIdx.x;
  for (int i = tid; i < L_SEQ; i += 1024) { v[i] = imp[i]; ix[i] = i; }
  __syncthreads();
  for (int k = 2; k <= L_SEQ; k <<= 1) {
    for (int j = k >> 1; j > 0; j >>= 1) {
#pragma unroll 1
      for (int t = tid; t < L_SEQ / 2; t += 1024) {
        const int i = ((t & ~(j - 1)) << 1) | (t & (j - 1));
        const int l = i | j;
        const float vi = v[i], vl = v[l];
        const bool desc = ((i & k) == 0);
        if (desc ? (vi < vl) : (vi > vl)) {
          v[i] = vl; v[l] = vi;
          const int tmp = ix[i]; ix[i] = ix[l]; ix[l] = tmp;
        }
      }
      __syncthreads();
    }
  }
  sel[tid] = ix[tid];
  __syncthreads();
  for (int k = 2; k <= K_SEL; k <<= 1) {
    for (int j = k >> 1; j > 0; j >>= 1) {
      if (tid < K_SEL / 2) {
        const int i = ((tid & ~(j - 1)) << 1) | (tid & (j - 1));
        const int l = i | j;
        const int si = sel[i], sl = sel[l];
        const bool asc = ((i & k) == 0);
        if (asc ? (si > sl) : (si < sl)) { sel[i] = sl; sel[l] = si; }
      }
      __syncthreads();
    }
  }
  if (tid == 0) sel[K_SEL] = L_SEQ - 1;
  __syncthreads();
  const int half = out_size >> 1;
  for (int i = tid; i < half; i += 1024) {
    const int idx2 = (i < K_SEL) ? sel[i] : sel[K_SEL];
    out[half + i] = idx2;
    out[i] = ids[idx2];
  }
}

// ============================================================
extern "C" void kernel_launch(void* const* d_in, const int* in_sizes, int n_in,
                              void* d_out, int out_size, void* d_ws, size_t ws_size,
                              hipStream_t stream) {
  const int*   ids   = (const int*)d_in[0];
  const float* table = (const float*)d_in[1];
  const float* wq    = (const float*)d_in[2];
  const float* wk    = (const float*)d_in[3];
  char* ws = (char*)d_ws;
  unsigned short* Wt = (unsigned short*)ws;                          // 12 MB [3072][2048]
  unsigned short* C  = (unsigned short*)(ws + 12ull * 1024 * 1024);  // 24 MB [4096][3072]
  float* imp = (float*)(ws + 36ull * 1024 * 1024);                   // 16 KB
  float* Z   = (float*)(ws + 36ull * 1024 * 1024 + 16384);           // 256 KB [16][4096]
  int* out = (int*)d_out;

  hipMemsetAsync(imp, 0, L_SEQ * sizeof(float), stream);
  hipMemsetAsync(Z, 0, NQ * L_SEQ * sizeof(float), stream);

  dim3 blk(256);
  prep_w<<<dim3(48, 32), blk, 0, stream>>>(wq, wk, Wt);
  gemm_qk<<<dim3(CSTR / 128, L_SEQ / 128), blk, 0, stream>>>(ids, table, Wt, C);
  rope_all<<<(L_SEQ * 24 * 64) / 256, blk, 0, stream>>>(C);
  attn_z<<<dim3(NCHUNK, NKV), blk, 0, stream>>>(C, C + 2048, Z);
  attn_col<<<dim3(NCHUNK, NKV), blk, 0, stream>>>(C, C + 2048, Z, imp);
  topk_kernel<<<1, 1024, 0, stream>>>(imp, ids, out, out_size);
}